// Round 3
// baseline (131.019 us; speedup 1.0000x reference)
//
#include <hip/hip_runtime.h>
#include <hip/hip_bf16.h>

typedef __attribute__((ext_vector_type(8))) short short8;
typedef __attribute__((ext_vector_type(4))) float float4v;

__device__ __forceinline__ unsigned short f2bf(float f) {
    // round-to-nearest-even fp32 -> bf16
    unsigned int u = __builtin_bit_cast(unsigned int, f);
    unsigned int lsb = (u >> 16) & 1u;
    u += 0x7fffu + lsb;
    return (unsigned short)(u >> 16);
}

__device__ __forceinline__ unsigned int pack2(float f0, float f1) {
    // round-half-up fp32x2 -> packed bf16x2
    unsigned int u0 = __builtin_bit_cast(unsigned int, f0) + 0x8000u;
    unsigned int u1 = __builtin_bit_cast(unsigned int, f1) + 0x8000u;
    return (u0 >> 16) | (u1 & 0xffff0000u);
}

// ---------------------------------------------------------------------------
// prep (merged): one dispatch.
// blocks [0,512):    LayerNorm + [wa|wb] projection via MFMA. n = b>>1,
//                    s-half = (b&1)*32; 128 thr = 2 waves, wave w: 16 s-rows.
//                    wa/wb fragments built on the fly (8 KB, L1-resident).
// blocks [512,1024): wo [1024][64] f32 -> woT [p][kk] bf16, kk = k*32+h
//                    (512*128 = 65536 = exact element count).
// ---------------------------------------------------------------------------
__global__ __launch_bounds__(128) void prep(
    const float* __restrict__ msa, const float* __restrict__ ln_w,
    const float* __restrict__ ln_b, const float* __restrict__ wa,
    const float* __restrict__ ba, const float* __restrict__ wb,
    const float* __restrict__ bb, const float* __restrict__ wo,
    unsigned short* __restrict__ a_out, unsigned short* __restrict__ b_out,
    unsigned short* __restrict__ woT)
{
    const int b = blockIdx.x;
    if (b >= 512) {                       // ---- woT transpose/convert ----
        const int idx = (b - 512) * 128 + threadIdx.x;
        const int hk = idx >> 6, p = idx & 63;
        const int h = hk >> 5, k = hk & 31;
        woT[(size_t)p * 1024 + k * 32 + h] = f2bf(wo[idx]);
        return;
    }

    // ---- LN + projections ----
    __shared__ __align__(16) unsigned short xn[2][16 * 72]; // stride 72: aligned b128, even banks
    const int n = b >> 1;
    const int w = threadIdx.x >> 6;
    const int lane = threadIdx.x & 63;
    const int s0 = (b & 1) * 32 + w * 16;
    const int sl = lane >> 2, dg = lane & 3;
    const int lm = lane & 15, q = lane >> 4;

    const float* __restrict__ row = msa + ((size_t)((s0 + sl) * 256 + n)) * 64;
    float4 x[4];
    #pragma unroll
    for (int ii = 0; ii < 4; ++ii) x[ii] = *(const float4*)(row + ii * 16 + dg * 4);

    float s = 0.f;
    #pragma unroll
    for (int ii = 0; ii < 4; ++ii) s += (x[ii].x + x[ii].y) + (x[ii].z + x[ii].w);
    s += __shfl_xor(s, 1, 4);
    s += __shfl_xor(s, 2, 4);
    const float mu = s * (1.f / 64.f);

    float v = 0.f;
    #pragma unroll
    for (int ii = 0; ii < 4; ++ii) {
        float a0 = x[ii].x - mu, a1 = x[ii].y - mu, a2 = x[ii].z - mu, a3 = x[ii].w - mu;
        v += (a0 * a0 + a1 * a1) + (a2 * a2 + a3 * a3);
    }
    v += __shfl_xor(v, 1, 4);
    v += __shfl_xor(v, 2, 4);
    const float rs = rsqrtf(v * (1.f / 64.f) + 1e-5f);

    #pragma unroll
    for (int ii = 0; ii < 4; ++ii) {
        const float4 lw = *(const float4*)(ln_w + ii * 16 + dg * 4);
        const float4 lb = *(const float4*)(ln_b + ii * 16 + dg * 4);
        uint2 pk;
        pk.x = pack2((x[ii].x - mu) * rs * lw.x + lb.x, (x[ii].y - mu) * rs * lw.y + lb.y);
        pk.y = pack2((x[ii].z - mu) * rs * lw.z + lb.z, (x[ii].w - mu) * rs * lw.w + lb.w);
        *(uint2*)(&xn[w][sl * 72 + ii * 16 + dg * 4]) = pk;
    }
    __syncthreads();

    // A-fragments: rows m = lm <-> s = s0+m, k = d
    short8 afr[2];
    #pragma unroll
    for (int ks = 0; ks < 2; ++ks)
        afr[ks] = *(const short8*)(&xn[w][lm * 72 + ks * 32 + q * 8]);

    float4v acc[4];
    #pragma unroll
    for (int c = 0; c < 4; ++c) acc[c] = (float4v){0.f, 0.f, 0.f, 0.f};
    #pragma unroll
    for (int c = 0; c < 4; ++c) {
        const int hp = c * 16 + lm;
        const float* __restrict__ wsrc = (hp < 32) ? (wa + hp) : (wb + hp - 32);
        #pragma unroll
        for (int ks = 0; ks < 2; ++ks) {
            short8 bfr;
            #pragma unroll
            for (int j = 0; j < 8; ++j)
                bfr[j] = (short)f2bf(wsrc[(ks * 32 + q * 8 + j) * 32]);
            acc[c] = __builtin_amdgcn_mfma_f32_16x16x32_bf16(afr[ks], bfr, acc[c], 0, 0, 0);
        }
    }

    // D: row = q*4+e -> s = s0+q*4+e, col = lm -> h' = c*16+lm
    #pragma unroll
    for (int c = 0; c < 4; ++c) {
        const int hp = c * 16 + lm;
        const float bias = (hp < 32) ? ba[hp] : bb[hp - 32];
        const float scale = (hp < 32) ? (1.f / 64.f) : 1.f;  // fold 1/S into a
        unsigned short* __restrict__ dst = (hp < 32) ? a_out : b_out;
        const int h = hp & 31;
        uint2 pk;
        pk.x = pack2((acc[c][0] + bias) * scale, (acc[c][1] + bias) * scale);
        pk.y = pack2((acc[c][2] + bias) * scale, (acc[c][3] + bias) * scale);
        *(uint2*)(dst + ((size_t)(n * 32 + h)) * 64 + s0 + q * 4) = pk;
    }
}

// ---------------------------------------------------------------------------
// fused_opm v3: 1024 blocks x 256 thr (4 waves); block b: bi = b>>4 fixed,
// loops 4 bj tiles (more blocks -> better tail/imbalance).
// Per 128x128 outer tile (16 (i,j) pairs, K=S=64):
//   stage 1: ALL 16 b-fragments preloaded at tile start (one latency batch),
//            wave w computes rows [w*32,w*32+32) x 128 cols in two 4-col
//            halves (caps acc1 live regs), packs C to LDS bf16 M[pair][k*40+h]
//            (pair stride 1272): b64 writes / b128 reads both bank-even.
//   stage 2: A = register-resident woT fragments (loaded once per block),
//            B = M from LDS; TWO independent MFMA chains (even/odd k-step)
//            to double stage-2 ILP. D rows = p -> contiguous float4 stores.
// ---------------------------------------------------------------------------
__global__ __launch_bounds__(256, 2) void fused_opm(
    const unsigned short* __restrict__ a_b, const unsigned short* __restrict__ b_b,
    const unsigned short* __restrict__ woT, const float* __restrict__ bo,
    float* __restrict__ out)
{
    __shared__ __align__(16) unsigned short ldsM[16 * 1272];

    const int b = blockIdx.x;
    const int bi = b >> 4;
    const int bj0 = (b & 15) << 2;
    const int w = threadIdx.x >> 6;
    const int lane = threadIdx.x & 63;
    const int lm = lane & 15, q = lane >> 4;

    // hoisted a-fragments: rows (i=bi*4+w, h=r*16+lm)
    short8 af[2][2];
    #pragma unroll
    for (int r = 0; r < 2; ++r)
        #pragma unroll
        for (int ks = 0; ks < 2; ++ks)
            af[r][ks] = *(const short8*)(a_b + ((size_t)(bi * 128 + w * 32 + r * 16 + lm)) * 64 + ks * 32 + q * 8);

    // register-resident woT A-fragments: rows p = w*16+lm
    short8 wf[32];
    #pragma unroll
    for (int ks = 0; ks < 32; ++ks)
        wf[ks] = *(const short8*)(woT + ((size_t)(w * 16 + lm)) * 1024 + ks * 32 + q * 8);

    const float4 bo4 = *(const float4*)(bo + w * 16 + q * 4);
    const int i = bi * 4 + (lm >> 2);   // stage-2 pair = lm
    const int jb = lm & 3;

    for (int t = 0; t < 4; ++t) {
        const int bj = bj0 + t;

        // ---- preload ALL 16 b-fragments for this tile (one latency batch) ----
        short8 bf[8][2];
        #pragma unroll
        for (int c = 0; c < 8; ++c)
            #pragma unroll
            for (int ks = 0; ks < 2; ++ks)
                bf[c][ks] = *(const short8*)(b_b + ((size_t)(bj * 128 + c * 16 + lm)) * 64 + ks * 32 + q * 8);

        // ---- stage 1: outer tile -> LDS (two 4-col halves) ----
        #pragma unroll
        for (int half = 0; half < 2; ++half) {
            float4v acc1[2][4];
            #pragma unroll
            for (int r = 0; r < 2; ++r)
                #pragma unroll
                for (int c2 = 0; c2 < 4; ++c2) acc1[r][c2] = (float4v){0.f, 0.f, 0.f, 0.f};
            #pragma unroll
            for (int c2 = 0; c2 < 4; ++c2)
                #pragma unroll
                for (int ks = 0; ks < 2; ++ks)
                    #pragma unroll
                    for (int r = 0; r < 2; ++r)
                        acc1[r][c2] = __builtin_amdgcn_mfma_f32_16x16x32_bf16(af[r][ks], bf[half * 4 + c2][ks], acc1[r][c2], 0, 0, 0);

            // C: row = w*32+r*16+q*4+e -> (i_loc=w, h), col = c*16+lm -> (j_loc=c>>1, k)
            #pragma unroll
            for (int r = 0; r < 2; ++r)
                #pragma unroll
                for (int c2 = 0; c2 < 4; ++c2) {
                    const int c = half * 4 + c2;
                    const int pair = w * 4 + (c >> 1);
                    const int k = ((c & 1) << 4) + lm;
                    const int h0 = r * 16 + q * 4;
                    uint2 pk;
                    pk.x = pack2(acc1[r][c2][0], acc1[r][c2][1]);
                    pk.y = pack2(acc1[r][c2][2], acc1[r][c2][3]);
                    *(uint2*)(ldsM + pair * 1272 + k * 40 + h0) = pk;
                }
        }
        __syncthreads();

        // ---- stage 2: out[p][pair] = woT[p][:] . M[pair][:], dual chains ----
        float4v acc2a = (float4v){0.f, 0.f, 0.f, 0.f};
        float4v acc2b = (float4v){0.f, 0.f, 0.f, 0.f};
        #pragma unroll
        for (int ks = 0; ks < 16; ++ks) {
            const short8 mf0 = *(const short8*)(ldsM + lm * 1272 + (2 * ks) * 40 + q * 8);
            const short8 mf1 = *(const short8*)(ldsM + lm * 1272 + (2 * ks + 1) * 40 + q * 8);
            acc2a = __builtin_amdgcn_mfma_f32_16x16x32_bf16(wf[2 * ks], mf0, acc2a, 0, 0, 0);
            acc2b = __builtin_amdgcn_mfma_f32_16x16x32_bf16(wf[2 * ks + 1], mf1, acc2b, 0, 0, 0);
        }

        const int j = bj * 4 + jb;
        float4 o;
        o.x = acc2a[0] + acc2b[0] + bo4.x;
        o.y = acc2a[1] + acc2b[1] + bo4.y;
        o.z = acc2a[2] + acc2b[2] + bo4.z;
        o.w = acc2a[3] + acc2b[3] + bo4.w;
        *(float4*)(out + ((size_t)(i * 256 + j)) * 64 + w * 16 + q * 4) = o;
        if (t < 3) __syncthreads();   // protect LDS before next tile's writes
    }
}

// ---------------------------------------------------------------------------
extern "C" void kernel_launch(void* const* d_in, const int* in_sizes, int n_in,
                              void* d_out, int out_size, void* d_ws, size_t ws_size,
                              hipStream_t stream) {
    const float* msa  = (const float*)d_in[0];
    const float* ln_w = (const float*)d_in[1];
    const float* ln_b = (const float*)d_in[2];
    const float* wa   = (const float*)d_in[3];
    const float* ba   = (const float*)d_in[4];
    const float* wb   = (const float*)d_in[5];
    const float* bb   = (const float*)d_in[6];
    const float* wo   = (const float*)d_in[7];
    const float* bo   = (const float*)d_in[8];
    float* out = (float*)d_out;

    // workspace (bf16): a (1 MB) | b (1 MB) | woT (128 KB)
    unsigned short* a_ws = (unsigned short*)d_ws;
    unsigned short* b_ws = a_ws + 256 * 32 * 64;
    unsigned short* woT  = b_ws + 256 * 32 * 64;

    prep<<<1024, 128, 0, stream>>>(msa, ln_w, ln_b, wa, ba, wb, bb, wo, a_ws, b_ws, woT);
    fused_opm<<<1024, 256, 0, stream>>>(a_ws, b_ws, woT, bo, out);
}

// Round 4
// 121.904 us; speedup vs baseline: 1.0748x; 1.0748x over previous
//
#include <hip/hip_runtime.h>
#include <hip/hip_bf16.h>

typedef __attribute__((ext_vector_type(8))) short short8;
typedef __attribute__((ext_vector_type(4))) float float4v;

__device__ __forceinline__ unsigned short f2bf(float f) {
    // round-to-nearest-even fp32 -> bf16
    unsigned int u = __builtin_bit_cast(unsigned int, f);
    unsigned int lsb = (u >> 16) & 1u;
    u += 0x7fffu + lsb;
    return (unsigned short)(u >> 16);
}

__device__ __forceinline__ unsigned int pack2(float f0, float f1) {
    // round-half-up fp32x2 -> packed bf16x2
    unsigned int u0 = __builtin_bit_cast(unsigned int, f0) + 0x8000u;
    unsigned int u1 = __builtin_bit_cast(unsigned int, f1) + 0x8000u;
    return (u0 >> 16) | (u1 & 0xffff0000u);
}

// ---------------------------------------------------------------------------
// prep (merged, one dispatch):
// blocks [0,512):    LayerNorm + [wa|wb] projection via MFMA. n = b>>1,
//                    s-half = (b&1)*32; 128 thr = 2 waves, wave w: 16 s-rows.
// blocks [512,1024): wo [1024][64] f32 -> woT [p][kk] bf16, kk = k*32+h.
// ---------------------------------------------------------------------------
__global__ __launch_bounds__(128) void prep(
    const float* __restrict__ msa, const float* __restrict__ ln_w,
    const float* __restrict__ ln_b, const float* __restrict__ wa,
    const float* __restrict__ ba, const float* __restrict__ wb,
    const float* __restrict__ bb, const float* __restrict__ wo,
    unsigned short* __restrict__ a_out, unsigned short* __restrict__ b_out,
    unsigned short* __restrict__ woT)
{
    const int b = blockIdx.x;
    if (b >= 512) {                       // ---- woT transpose/convert ----
        const int idx = (b - 512) * 128 + threadIdx.x;
        const int hk = idx >> 6, p = idx & 63;
        const int h = hk >> 5, k = hk & 31;
        woT[(size_t)p * 1024 + k * 32 + h] = f2bf(wo[idx]);
        return;
    }

    // ---- LN + projections ----
    __shared__ __align__(16) unsigned short xn[2][16 * 72]; // stride 72: aligned b128, even banks
    const int n = b >> 1;
    const int w = threadIdx.x >> 6;
    const int lane = threadIdx.x & 63;
    const int s0 = (b & 1) * 32 + w * 16;
    const int sl = lane >> 2, dg = lane & 3;
    const int lm = lane & 15, q = lane >> 4;

    const float* __restrict__ row = msa + ((size_t)((s0 + sl) * 256 + n)) * 64;
    float4 x[4];
    #pragma unroll
    for (int ii = 0; ii < 4; ++ii) x[ii] = *(const float4*)(row + ii * 16 + dg * 4);

    float s = 0.f;
    #pragma unroll
    for (int ii = 0; ii < 4; ++ii) s += (x[ii].x + x[ii].y) + (x[ii].z + x[ii].w);
    s += __shfl_xor(s, 1, 4);
    s += __shfl_xor(s, 2, 4);
    const float mu = s * (1.f / 64.f);

    float v = 0.f;
    #pragma unroll
    for (int ii = 0; ii < 4; ++ii) {
        float a0 = x[ii].x - mu, a1 = x[ii].y - mu, a2 = x[ii].z - mu, a3 = x[ii].w - mu;
        v += (a0 * a0 + a1 * a1) + (a2 * a2 + a3 * a3);
    }
    v += __shfl_xor(v, 1, 4);
    v += __shfl_xor(v, 2, 4);
    const float rs = rsqrtf(v * (1.f / 64.f) + 1e-5f);

    #pragma unroll
    for (int ii = 0; ii < 4; ++ii) {
        const float4 lw = *(const float4*)(ln_w + ii * 16 + dg * 4);
        const float4 lb = *(const float4*)(ln_b + ii * 16 + dg * 4);
        uint2 pk;
        pk.x = pack2((x[ii].x - mu) * rs * lw.x + lb.x, (x[ii].y - mu) * rs * lw.y + lb.y);
        pk.y = pack2((x[ii].z - mu) * rs * lw.z + lb.z, (x[ii].w - mu) * rs * lw.w + lb.w);
        *(uint2*)(&xn[w][sl * 72 + ii * 16 + dg * 4]) = pk;
    }
    __syncthreads();

    short8 afr[2];
    #pragma unroll
    for (int ks = 0; ks < 2; ++ks)
        afr[ks] = *(const short8*)(&xn[w][lm * 72 + ks * 32 + q * 8]);

    float4v acc[4];
    #pragma unroll
    for (int c = 0; c < 4; ++c) acc[c] = (float4v){0.f, 0.f, 0.f, 0.f};
    #pragma unroll
    for (int c = 0; c < 4; ++c) {
        const int hp = c * 16 + lm;
        const float* __restrict__ wsrc = (hp < 32) ? (wa + hp) : (wb + hp - 32);
        #pragma unroll
        for (int ks = 0; ks < 2; ++ks) {
            short8 bfr;
            #pragma unroll
            for (int j = 0; j < 8; ++j)
                bfr[j] = (short)f2bf(wsrc[(ks * 32 + q * 8 + j) * 32]);
            acc[c] = __builtin_amdgcn_mfma_f32_16x16x32_bf16(afr[ks], bfr, acc[c], 0, 0, 0);
        }
    }

    #pragma unroll
    for (int c = 0; c < 4; ++c) {
        const int hp = c * 16 + lm;
        const float bias = (hp < 32) ? ba[hp] : bb[hp - 32];
        const float scale = (hp < 32) ? (1.f / 64.f) : 1.f;  // fold 1/S into a
        unsigned short* __restrict__ dst = (hp < 32) ? a_out : b_out;
        const int h = hp & 31;
        uint2 pk;
        pk.x = pack2((acc[c][0] + bias) * scale, (acc[c][1] + bias) * scale);
        pk.y = pack2((acc[c][2] + bias) * scale, (acc[c][3] + bias) * scale);
        *(uint2*)(dst + ((size_t)(n * 32 + h)) * 64 + s0 + q * 4) = pk;
    }
}

// ---------------------------------------------------------------------------
// fused_opm v4: 512 blocks x 256 thr (4 waves); block b: bi = b>>3 fixed,
// loops 8 bj tiles (wf amortized over 8 tiles — R3's 1024x4 grid regressed).
// Per 128x128 outer tile (16 (i,j) pairs, K=S=64):
//   stage 1: wave w computes rows [w*32,w*32+32) x 128 cols in two 4-col
//            halves; packs C bf16 to LDS M[pair][k*40+h] (pair stride 1272).
//   stage 2 (K-SPLIT, the v4 change): wave w contracts kk-slice
//            k in [w*8,w*8+8) for ALL 64 p (4 m-tiles). Each M element is
//            read ONCE per block (was 4x): per ks one shared b128 read feeds
//            4 MFMAs. wf = [4 mt][8 ks] register-resident woT (same 128
//            VGPRs, loaded once per block). fp32 partials -> 16 KB ldsR,
//            reduced over the 4 kk-slices by wave w = mt w. Still 2
//            barriers/tile (ldsR reuse fenced by next tile's bar1).
// LDS traffic/tile: 32 (s1 w) + 32 (s2 r) + 16 (red w) + 16 (red r) = 96 KB
// vs v3's 160 KB.
// ---------------------------------------------------------------------------
__global__ __launch_bounds__(256, 2) void fused_opm(
    const unsigned short* __restrict__ a_b, const unsigned short* __restrict__ b_b,
    const unsigned short* __restrict__ woT, const float* __restrict__ bo,
    float* __restrict__ out)
{
    __shared__ __align__(16) unsigned short ldsM[16 * 1272];
    __shared__ __align__(16) float ldsR[4096];   // [kh][mt][lane][e]

    const int b = blockIdx.x;
    const int bi = b >> 3;
    const int bj0 = (b & 7) << 3;
    const int w = threadIdx.x >> 6;
    const int lane = threadIdx.x & 63;
    const int lm = lane & 15, q = lane >> 4;

    // stage-1 a-fragments: rows (i=bi*4+w, h=r*16+lm)
    short8 af[2][2];
    #pragma unroll
    for (int r = 0; r < 2; ++r)
        #pragma unroll
        for (int ks = 0; ks < 2; ++ks)
            af[r][ks] = *(const short8*)(a_b + ((size_t)(bi * 128 + w * 32 + r * 16 + lm)) * 64 + ks * 32 + q * 8);

    // register-resident woT: wf[mt][ks] = rows p = mt*16+lm, k = w*8+ks, h = q*8..
    short8 wf[4][8];
    #pragma unroll
    for (int mt = 0; mt < 4; ++mt)
        #pragma unroll
        for (int ks = 0; ks < 8; ++ks)
            wf[mt][ks] = *(const short8*)(woT + ((size_t)(mt * 16 + lm)) * 1024 + (w * 8 + ks) * 32 + q * 8);

    const float4 bo4 = *(const float4*)(bo + w * 16 + q * 4);
    const int i = bi * 4 + (lm >> 2);   // finalize: pair = lm
    const int jb = lm & 3;

    for (int t = 0; t < 8; ++t) {
        const int bj = bj0 + t;

        // ---- stage 1: outer tile -> LDS (two 4-col halves) ----
        #pragma unroll
        for (int half = 0; half < 2; ++half) {
            short8 bf[4][2];
            #pragma unroll
            for (int c2 = 0; c2 < 4; ++c2)
                #pragma unroll
                for (int ks = 0; ks < 2; ++ks) {
                    const int c = half * 4 + c2;
                    bf[c2][ks] = *(const short8*)(b_b + ((size_t)(bj * 128 + c * 16 + lm)) * 64 + ks * 32 + q * 8);
                }
            float4v acc1[2][4];
            #pragma unroll
            for (int r = 0; r < 2; ++r)
                #pragma unroll
                for (int c2 = 0; c2 < 4; ++c2) acc1[r][c2] = (float4v){0.f, 0.f, 0.f, 0.f};
            #pragma unroll
            for (int c2 = 0; c2 < 4; ++c2)
                #pragma unroll
                for (int ks = 0; ks < 2; ++ks)
                    #pragma unroll
                    for (int r = 0; r < 2; ++r)
                        acc1[r][c2] = __builtin_amdgcn_mfma_f32_16x16x32_bf16(af[r][ks], bf[c2][ks], acc1[r][c2], 0, 0, 0);

            // C: row = w*32+r*16+q*4+e -> (i_loc=w, h = r*16+q*4+e), col = c*16+lm -> (j_loc=c>>1, k)
            #pragma unroll
            for (int r = 0; r < 2; ++r)
                #pragma unroll
                for (int c2 = 0; c2 < 4; ++c2) {
                    const int c = half * 4 + c2;
                    const int pair = w * 4 + (c >> 1);
                    const int k = ((c & 1) << 4) + lm;
                    const int h0 = r * 16 + q * 4;
                    uint2 pk;
                    pk.x = pack2(acc1[r][c2][0], acc1[r][c2][1]);
                    pk.y = pack2(acc1[r][c2][2], acc1[r][c2][3]);
                    *(uint2*)(ldsM + pair * 1272 + k * 40 + h0) = pk;
                }
        }
        __syncthreads();   // bar1: M complete (also fences ldsR reuse from prev tile)

        // ---- stage 2: k-split. wave w: k in [w*8,w*8+8), all 64 p ----
        float4v acc2[4];
        #pragma unroll
        for (int mt = 0; mt < 4; ++mt) acc2[mt] = (float4v){0.f, 0.f, 0.f, 0.f};
        #pragma unroll
        for (int ks = 0; ks < 8; ++ks) {
            const short8 mf = *(const short8*)(ldsM + lm * 1272 + (w * 8 + ks) * 40 + q * 8);
            #pragma unroll
            for (int mt = 0; mt < 4; ++mt)
                acc2[mt] = __builtin_amdgcn_mfma_f32_16x16x32_bf16(wf[mt][ks], mf, acc2[mt], 0, 0, 0);
        }

        // partials -> ldsR[(w*4+mt)*256 + lane*4 + e]
        #pragma unroll
        for (int mt = 0; mt < 4; ++mt)
            *(float4v*)(&ldsR[((w * 4 + mt) << 8) + (lane << 2)]) = acc2[mt];
        __syncthreads();   // bar2: partials complete (also: all s2 M-reads done -> next s1w safe)

        // ---- finalize: wave w sums mt = w over the 4 kk-slices ----
        float4v sum = *(const float4v*)(&ldsR[(w << 8) + (lane << 2)]);
        #pragma unroll
        for (int kh = 1; kh < 4; ++kh)
            sum += *(const float4v*)(&ldsR[((kh * 4 + w) << 8) + (lane << 2)]);

        const int j = bj * 4 + jb;
        float4 o;
        o.x = sum[0] + bo4.x;
        o.y = sum[1] + bo4.y;
        o.z = sum[2] + bo4.z;
        o.w = sum[3] + bo4.w;
        *(float4*)(out + ((size_t)(i * 256 + j)) * 64 + w * 16 + q * 4) = o;
    }
}

// ---------------------------------------------------------------------------
extern "C" void kernel_launch(void* const* d_in, const int* in_sizes, int n_in,
                              void* d_out, int out_size, void* d_ws, size_t ws_size,
                              hipStream_t stream) {
    const float* msa  = (const float*)d_in[0];
    const float* ln_w = (const float*)d_in[1];
    const float* ln_b = (const float*)d_in[2];
    const float* wa   = (const float*)d_in[3];
    const float* ba   = (const float*)d_in[4];
    const float* wb   = (const float*)d_in[5];
    const float* bb   = (const float*)d_in[6];
    const float* wo   = (const float*)d_in[7];
    const float* bo   = (const float*)d_in[8];
    float* out = (float*)d_out;

    // workspace (bf16): a (1 MB) | b (1 MB) | woT (128 KB)
    unsigned short* a_ws = (unsigned short*)d_ws;
    unsigned short* b_ws = a_ws + 256 * 32 * 64;
    unsigned short* woT  = b_ws + 256 * 32 * 64;

    prep<<<1024, 128, 0, stream>>>(msa, ln_w, ln_b, wa, ba, wb, bb, wo, a_ws, b_ws, woT);
    fused_opm<<<512, 256, 0, stream>>>(a_ws, b_ws, woT, bo, out);
}

// Round 5
// 104.629 us; speedup vs baseline: 1.2522x; 1.1651x over previous
//
#include <hip/hip_runtime.h>
#include <hip/hip_bf16.h>

typedef __attribute__((ext_vector_type(8))) short short8;
typedef __attribute__((ext_vector_type(4))) float float4v;

typedef __attribute__((address_space(3))) unsigned int lds_u32;
typedef __attribute__((address_space(1))) const unsigned int glb_u32;

__device__ __forceinline__ unsigned short f2bf(float f) {
    // round-to-nearest-even fp32 -> bf16
    unsigned int u = __builtin_bit_cast(unsigned int, f);
    unsigned int lsb = (u >> 16) & 1u;
    u += 0x7fffu + lsb;
    return (unsigned short)(u >> 16);
}

__device__ __forceinline__ unsigned int pack2(float f0, float f1) {
    // round-half-up fp32x2 -> packed bf16x2
    unsigned int u0 = __builtin_bit_cast(unsigned int, f0) + 0x8000u;
    unsigned int u1 = __builtin_bit_cast(unsigned int, f1) + 0x8000u;
    return (u0 >> 16) | (u1 & 0xffff0000u);
}

// ---------------------------------------------------------------------------
// prep (merged, one dispatch):
// blocks [0,512):    LayerNorm + [wa|wb] projection via MFMA. n = b>>1,
//                    s-half = (b&1)*32; 128 thr = 2 waves, wave w: 16 s-rows.
//                    b_out is stored with XOR-SWIZZLED k-octets:
//                    row R = n*32+h, element s stored at
//                    R*64 + ((s>>3 ^ (R&7))<<3) + (s&7)  — so fused's
//                    global_load_lds (linear copy) yields conflict-free
//                    ds_read_b128 b-fragments.
// blocks [512,1024): wo [1024][64] f32 -> woT [p][kk] bf16, kk = k*32+h.
// ---------------------------------------------------------------------------
__global__ __launch_bounds__(128) void prep(
    const float* __restrict__ msa, const float* __restrict__ ln_w,
    const float* __restrict__ ln_b, const float* __restrict__ wa,
    const float* __restrict__ ba, const float* __restrict__ wb,
    const float* __restrict__ bb, const float* __restrict__ wo,
    unsigned short* __restrict__ a_out, unsigned short* __restrict__ b_out,
    unsigned short* __restrict__ woT)
{
    const int b = blockIdx.x;
    if (b >= 512) {                       // ---- woT transpose/convert ----
        const int idx = (b - 512) * 128 + threadIdx.x;
        const int hk = idx >> 6, p = idx & 63;
        const int h = hk >> 5, k = hk & 31;
        woT[(size_t)p * 1024 + k * 32 + h] = f2bf(wo[idx]);
        return;
    }

    // ---- LN + projections ----
    __shared__ __align__(16) unsigned short xn[2][16 * 72];
    const int n = b >> 1;
    const int w = threadIdx.x >> 6;
    const int lane = threadIdx.x & 63;
    const int s0 = (b & 1) * 32 + w * 16;
    const int sl = lane >> 2, dg = lane & 3;
    const int lm = lane & 15, q = lane >> 4;

    const float* __restrict__ row = msa + ((size_t)((s0 + sl) * 256 + n)) * 64;
    float4 x[4];
    #pragma unroll
    for (int ii = 0; ii < 4; ++ii) x[ii] = *(const float4*)(row + ii * 16 + dg * 4);

    float s = 0.f;
    #pragma unroll
    for (int ii = 0; ii < 4; ++ii) s += (x[ii].x + x[ii].y) + (x[ii].z + x[ii].w);
    s += __shfl_xor(s, 1, 4);
    s += __shfl_xor(s, 2, 4);
    const float mu = s * (1.f / 64.f);

    float v = 0.f;
    #pragma unroll
    for (int ii = 0; ii < 4; ++ii) {
        float a0 = x[ii].x - mu, a1 = x[ii].y - mu, a2 = x[ii].z - mu, a3 = x[ii].w - mu;
        v += (a0 * a0 + a1 * a1) + (a2 * a2 + a3 * a3);
    }
    v += __shfl_xor(v, 1, 4);
    v += __shfl_xor(v, 2, 4);
    const float rs = rsqrtf(v * (1.f / 64.f) + 1e-5f);

    #pragma unroll
    for (int ii = 0; ii < 4; ++ii) {
        const float4 lw = *(const float4*)(ln_w + ii * 16 + dg * 4);
        const float4 lb = *(const float4*)(ln_b + ii * 16 + dg * 4);
        uint2 pk;
        pk.x = pack2((x[ii].x - mu) * rs * lw.x + lb.x, (x[ii].y - mu) * rs * lw.y + lb.y);
        pk.y = pack2((x[ii].z - mu) * rs * lw.z + lb.z, (x[ii].w - mu) * rs * lw.w + lb.w);
        *(uint2*)(&xn[w][sl * 72 + ii * 16 + dg * 4]) = pk;
    }
    __syncthreads();

    short8 afr[2];
    #pragma unroll
    for (int ks = 0; ks < 2; ++ks)
        afr[ks] = *(const short8*)(&xn[w][lm * 72 + ks * 32 + q * 8]);

    float4v acc[4];
    #pragma unroll
    for (int c = 0; c < 4; ++c) acc[c] = (float4v){0.f, 0.f, 0.f, 0.f};
    #pragma unroll
    for (int c = 0; c < 4; ++c) {
        const int hp = c * 16 + lm;
        const float* __restrict__ wsrc = (hp < 32) ? (wa + hp) : (wb + hp - 32);
        #pragma unroll
        for (int ks = 0; ks < 2; ++ks) {
            short8 bfr;
            #pragma unroll
            for (int j = 0; j < 8; ++j)
                bfr[j] = (short)f2bf(wsrc[(ks * 32 + q * 8 + j) * 32]);
            acc[c] = __builtin_amdgcn_mfma_f32_16x16x32_bf16(afr[ks], bfr, acc[c], 0, 0, 0);
        }
    }

    #pragma unroll
    for (int c = 0; c < 4; ++c) {
        const int hp = c * 16 + lm;
        const float bias = (hp < 32) ? ba[hp] : bb[hp - 32];
        const float scale = (hp < 32) ? (1.f / 64.f) : 1.f;  // fold 1/S into a
        uint2 pk;
        pk.x = pack2((acc[c][0] + bias) * scale, (acc[c][1] + bias) * scale);
        pk.y = pack2((acc[c][2] + bias) * scale, (acc[c][3] + bias) * scale);
        const int sbase = s0 + q * 4;
        if (hp < 32) {
            *(uint2*)(a_out + ((size_t)(n * 32 + hp)) * 64 + sbase) = pk;
        } else {
            const int R = n * 32 + (hp - 32);
            const int o = sbase >> 3;
            const int phys = (R << 6) + (((o ^ (R & 7)) << 3) | (sbase & 7));
            *(uint2*)(b_out + phys) = pk;
        }
    }
}

// ---------------------------------------------------------------------------
// fused_opm v5: 512 blocks x 256 thr (4 waves); block b: bi = b>>3, 8 bj tiles.
// v5 change: b-tiles staged through double-buffered LDS via async
// global_load_lds (16B, zero VGPR cost) with XOR-swizzled octet layout ->
// stage-1 b-frags are conflict-free(2-way) ds_read_b128 from LDS instead of
// ~600-cyc L2 loads on the critical path. Fill for tile t+2 issues right
// after bar1(t) (its buffer's last reads ended at stage1(t)).
// stage 2 = R2-style full-K per wave (k-split + ldsR dropped: measured
// worthless, and the 16 KB pays for ldsB). LDS 73.5 KB -> 2 blocks/CU.
// ---------------------------------------------------------------------------
__global__ __launch_bounds__(256, 2) void fused_opm(
    const unsigned short* __restrict__ a_b, const unsigned short* __restrict__ b_swz,
    const unsigned short* __restrict__ woT, const float* __restrict__ bo,
    float* __restrict__ out)
{
    __shared__ __align__(16) unsigned short ldsB[2][128 * 64];  // swizzled b-tiles
    __shared__ __align__(16) unsigned short ldsM[16 * 1272];

    const int b = blockIdx.x;
    const int bi = b >> 3;
    const int bj0 = (b & 7) << 3;
    const int w = threadIdx.x >> 6;
    const int lane = threadIdx.x & 63;
    const int lm = lane & 15, q = lane >> 4;

    // async fill: copy 16 KB b-tile bjx (linear, pre-swizzled in prep) into buf
    auto fill = [&](int buf, int bjx) {
        #pragma unroll
        for (int li = 0; li < 4; ++li) {
            const int chunk = w * 4 + li;                       // 16 x 1 KB chunks
            const unsigned short* g = b_swz + (size_t)bjx * 8192 + chunk * 512 + lane * 8;
            __builtin_amdgcn_global_load_lds((glb_u32*)g,
                (lds_u32*)(&ldsB[buf][chunk * 512]), 16, 0, 0);
        }
    };

    // hoisted a-fragments: rows (i=bi*4+w, h=r*16+lm)
    short8 af[2][2];
    #pragma unroll
    for (int r = 0; r < 2; ++r)
        #pragma unroll
        for (int ks = 0; ks < 2; ++ks)
            af[r][ks] = *(const short8*)(a_b + ((size_t)(bi * 128 + w * 32 + r * 16 + lm)) * 64 + ks * 32 + q * 8);

    // register-resident woT: rows p = w*16+lm
    short8 wf[32];
    #pragma unroll
    for (int ks = 0; ks < 32; ++ks)
        wf[ks] = *(const short8*)(woT + ((size_t)(w * 16 + lm)) * 1024 + ks * 32 + q * 8);

    fill(0, bj0 + 0);
    fill(1, bj0 + 1);

    const float4 bo4 = *(const float4*)(bo + w * 16 + q * 4);
    const int i = bi * 4 + (lm >> 2);   // stage-2 pair = lm
    const int jb = lm & 3;

    __syncthreads();   // fills of buf0/buf1 complete (vmcnt drain at barrier)

    for (int t = 0; t < 8; ++t) {
        const int bj = bj0 + t;
        const int buf = t & 1;

        // ---- stage 1: outer tile -> ldsM (b-frags from ldsB, swizzled) ----
        #pragma unroll
        for (int half = 0; half < 2; ++half) {
            short8 bf[4][2];
            #pragma unroll
            for (int c2 = 0; c2 < 4; ++c2)
                #pragma unroll
                for (int ks = 0; ks < 2; ++ks) {
                    const int rrow = (half * 4 + c2) * 16 + lm;
                    const int o = ks * 4 + q;                   // k-octet
                    bf[c2][ks] = *(const short8*)(&ldsB[buf][(rrow << 6) + ((o ^ (rrow & 7)) << 3)]);
                }
            float4v acc1[2][4];
            #pragma unroll
            for (int r = 0; r < 2; ++r)
                #pragma unroll
                for (int c2 = 0; c2 < 4; ++c2) acc1[r][c2] = (float4v){0.f, 0.f, 0.f, 0.f};
            #pragma unroll
            for (int c2 = 0; c2 < 4; ++c2)
                #pragma unroll
                for (int ks = 0; ks < 2; ++ks)
                    #pragma unroll
                    for (int r = 0; r < 2; ++r)
                        acc1[r][c2] = __builtin_amdgcn_mfma_f32_16x16x32_bf16(af[r][ks], bf[c2][ks], acc1[r][c2], 0, 0, 0);

            // C: row = w*32+r*16+q*4+e -> (i_loc=w, h), col = c*16+lm -> (j_loc=c>>1, k)
            #pragma unroll
            for (int r = 0; r < 2; ++r)
                #pragma unroll
                for (int c2 = 0; c2 < 4; ++c2) {
                    const int c = half * 4 + c2;
                    const int pair = w * 4 + (c >> 1);
                    const int k = ((c & 1) << 4) + lm;
                    const int h0 = r * 16 + q * 4;
                    uint2 pk;
                    pk.x = pack2(acc1[r][c2][0], acc1[r][c2][1]);
                    pk.y = pack2(acc1[r][c2][2], acc1[r][c2][3]);
                    *(uint2*)(ldsM + pair * 1272 + k * 40 + h0) = pk;
                }
        }
        __syncthreads();   // bar1: M ready; all ldsB[buf] reads done

        // refill this buffer for tile t+2 (async, completes by bar2's drain)
        if (t < 6) fill(buf, bj0 + t + 2);

        // ---- stage 2: out[p][pair] = woT[p][:] . M[pair][:], dual chains ----
        float4v acc2a = (float4v){0.f, 0.f, 0.f, 0.f};
        float4v acc2b = (float4v){0.f, 0.f, 0.f, 0.f};
        #pragma unroll
        for (int ks = 0; ks < 16; ++ks) {
            const short8 mf0 = *(const short8*)(ldsM + lm * 1272 + (2 * ks) * 40 + q * 8);
            const short8 mf1 = *(const short8*)(ldsM + lm * 1272 + (2 * ks + 1) * 40 + q * 8);
            acc2a = __builtin_amdgcn_mfma_f32_16x16x32_bf16(wf[2 * ks], mf0, acc2a, 0, 0, 0);
            acc2b = __builtin_amdgcn_mfma_f32_16x16x32_bf16(wf[2 * ks + 1], mf1, acc2b, 0, 0, 0);
        }

        const int j = bj * 4 + jb;
        float4 o;
        o.x = acc2a[0] + acc2b[0] + bo4.x;
        o.y = acc2a[1] + acc2b[1] + bo4.y;
        o.z = acc2a[2] + acc2b[2] + bo4.z;
        o.w = acc2a[3] + acc2b[3] + bo4.w;
        *(float4*)(out + ((size_t)(i * 256 + j)) * 64 + w * 16 + q * 4) = o;
        __syncthreads();   // bar2: ldsM reads done; next stage1 may rewrite
    }
}

// ---------------------------------------------------------------------------
extern "C" void kernel_launch(void* const* d_in, const int* in_sizes, int n_in,
                              void* d_out, int out_size, void* d_ws, size_t ws_size,
                              hipStream_t stream) {
    const float* msa  = (const float*)d_in[0];
    const float* ln_w = (const float*)d_in[1];
    const float* ln_b = (const float*)d_in[2];
    const float* wa   = (const float*)d_in[3];
    const float* ba   = (const float*)d_in[4];
    const float* wb   = (const float*)d_in[5];
    const float* bb   = (const float*)d_in[6];
    const float* wo   = (const float*)d_in[7];
    const float* bo   = (const float*)d_in[8];
    float* out = (float*)d_out;

    // workspace (bf16): a (1 MB) | b (1 MB, octet-swizzled) | woT (128 KB)
    unsigned short* a_ws = (unsigned short*)d_ws;
    unsigned short* b_ws = a_ws + 256 * 32 * 64;
    unsigned short* woT  = b_ws + 256 * 32 * 64;

    prep<<<1024, 128, 0, stream>>>(msa, ln_w, ln_b, wa, ba, wb, bb, wo, a_ws, b_ws, woT);
    fused_opm<<<512, 256, 0, stream>>>(a_ws, b_ws, woT, bo, out);
}